// Round 17
// baseline (1187.116 us; speedup 1.0000x reference)
//
#include <hip/hip_runtime.h>
#include <hip/hip_cooperative_groups.h>

namespace cg = cooperative_groups;

#define NN 50000
#define NE 800000
#define KD 128    // inner dim (IN_C == HID_C == 128)
#define NBUK 196  // ceil(NN/256) buckets by dst>>8
#define CHUNK 2048
#define NCH 391   // ceil(NE/CHUNK)
#define SLACK 8192
#define GBLK 1024 // cooperative grid: 4 blocks/CU x 256 CU

typedef __attribute__((ext_vector_type(8))) short short8;
typedef __attribute__((ext_vector_type(4))) float f32x4;
typedef __attribute__((ext_vector_type(4))) unsigned short us4;

// ---------------- bf16 helpers ----------------
__device__ __forceinline__ void splitbf(float x, short& h, short& l) {
    unsigned int u = __float_as_uint(x);
    unsigned int r = u + 0x8000u;
    short hh = (short)(r >> 16);
    float hf = __uint_as_float(((unsigned int)(unsigned short)hh) << 16);
    float lo = x - hf;
    unsigned int u2 = __float_as_uint(lo) + 0x8000u;
    h = hh;
    l = (short)(u2 >> 16);
}
__device__ __forceinline__ unsigned short f2bf(float x) {   // RTNE
    unsigned int u = __float_as_uint(x);
    unsigned int r = u + 0x7FFFu + ((u >> 16) & 1u);
    return (unsigned short)(r >> 16);
}
__device__ __forceinline__ float bf2f(unsigned short b) {
    return __uint_as_float(((unsigned int)b) << 16);
}

// ---------------- shared phase bodies (used by mono + fallback) ----------------
// GEMM phase: W hi/lo read direct from global (L2-hot). MFMA order identical to R16.
template<int CO, bool XBF, int EPI>
__device__ __forceinline__ void mgemm_body(
    const void* __restrict__ Xin,
    const unsigned short* __restrict__ Wh, const unsigned short* __restrict__ Wl,
    const float* __restrict__ dinv, const float* __restrict__ bout,
    void* __restrict__ outAv, int vb, int t)
{
    const int wv = t >> 6, l = t & 63, q = l >> 4, lr = l & 15;
    const int row0 = vb * 64 + wv * 16;
    constexpr int NCT = CO / 16;

    f32x4 acc[NCT];
#pragma unroll
    for (int ct = 0; ct < NCT; ++ct) acc[ct] = (f32x4){0.f, 0.f, 0.f, 0.f};

    int xrow = row0 + lr; if (xrow > NN - 1) xrow = NN - 1;

#pragma unroll
    for (int kk = 0; kk < 4; ++kk) {
        short8 ah, al;
        if (XBF) {
            ah = *(const short8*)((const unsigned short*)Xin + (size_t)xrow * KD + q * 8 + kk * 32);
        } else {
            const float* xb = (const float*)Xin + (size_t)xrow * KD + q * 8 + kk * 32;
            float4 x0 = *(const float4*)xb;
            float4 x1 = *(const float4*)(xb + 4);
            float xs[8] = {x0.x, x0.y, x0.z, x0.w, x1.x, x1.y, x1.z, x1.w};
#pragma unroll
            for (int j = 0; j < 8; ++j) { short hh, ll; splitbf(xs[j], hh, ll); ah[j] = hh; al[j] = ll; }
        }
        int Gg = kk * 4 + q;
#pragma unroll
        for (int ct = 0; ct < NCT; ++ct) {
            int c = ct * 16 + lr;
            short8 bh = *(const short8*)(Wh + c * KD + Gg * 8);
            short8 bl = *(const short8*)(Wl + c * KD + Gg * 8);
            acc[ct] = __builtin_amdgcn_mfma_f32_16x16x32_bf16(ah, bh, acc[ct], 0, 0, 0);
            acc[ct] = __builtin_amdgcn_mfma_f32_16x16x32_bf16(ah, bl, acc[ct], 0, 0, 0);
            if (!XBF)
                acc[ct] = __builtin_amdgcn_mfma_f32_16x16x32_bf16(al, bh, acc[ct], 0, 0, 0);
        }
    }

    float dv[4]; int rok[4];
#pragma unroll
    for (int r = 0; r < 4; ++r) {
        int row = row0 + q * 4 + r;
        rok[r] = (row < NN);
        dv[r] = (EPI == 0 && rok[r]) ? dinv[row] : 0.f;
    }
#pragma unroll
    for (int ct = 0; ct < NCT; ++ct) {
        int c = ct * 16 + lr;
        float bc = (EPI == 1) ? bout[c] : 0.f;
#pragma unroll
        for (int r = 0; r < 4; ++r) {
            int row = row0 + q * 4 + r;
            if (rok[r]) {
                float v = acc[ct][r];
                if (EPI == 0) ((unsigned short*)outAv)[(size_t)row * CO + c] = f2bf(v * dv[r]);
                else          ((float*)outAv)[(size_t)row * CO + c] = fmaxf(0.f, v + bc);
            }
        }
    }
}

// gather body for one node d (R9-proven parity-half loop), per-wave
__device__ __forceinline__ void gather_node(
    const unsigned short* __restrict__ hp, unsigned short* __restrict__ outX,
    const int* __restrict__ begp, const int* __restrict__ endpp,
    const int* __restrict__ col, const float* __restrict__ dinv,
    float4 bb, int d, int h, int sl)
{
    int beg = begp[d], end = endpp[d];

    float4 a0 = make_float4(0.f, 0.f, 0.f, 0.f);
    float4 a1 = make_float4(0.f, 0.f, 0.f, 0.f);
    float4 a2 = make_float4(0.f, 0.f, 0.f, 0.f);
    float4 a3 = make_float4(0.f, 0.f, 0.f, 0.f);

    if (h == 0) {
        us4 v = *(const us4*)(hp + (size_t)d * KD);
        a0.x = bf2f(v[0]); a0.y = bf2f(v[1]); a0.z = bf2f(v[2]); a0.w = bf2f(v[3]);
    }

    int j = beg + h;
    for (; j + 6 < end; j += 8) {
        int s0 = col[j],     s1 = col[j + 2];
        int s2 = col[j + 4], s3 = col[j + 6];
        us4 v0 = *(const us4*)(hp + (size_t)s0 * KD);
        us4 v1 = *(const us4*)(hp + (size_t)s1 * KD);
        us4 v2 = *(const us4*)(hp + (size_t)s2 * KD);
        us4 v3 = *(const us4*)(hp + (size_t)s3 * KD);
        a0.x += bf2f(v0[0]); a0.y += bf2f(v0[1]); a0.z += bf2f(v0[2]); a0.w += bf2f(v0[3]);
        a1.x += bf2f(v1[0]); a1.y += bf2f(v1[1]); a1.z += bf2f(v1[2]); a1.w += bf2f(v1[3]);
        a2.x += bf2f(v2[0]); a2.y += bf2f(v2[1]); a2.z += bf2f(v2[2]); a2.w += bf2f(v2[3]);
        a3.x += bf2f(v3[0]); a3.y += bf2f(v3[1]); a3.z += bf2f(v3[2]); a3.w += bf2f(v3[3]);
    }
    for (; j < end; j += 2) {
        int s = col[j];
        us4 v = *(const us4*)(hp + (size_t)s * KD);
        a0.x += bf2f(v[0]); a0.y += bf2f(v[1]); a0.z += bf2f(v[2]); a0.w += bf2f(v[3]);
    }

    float4 tt;
    tt.x = (a0.x + a1.x) + (a2.x + a3.x);
    tt.y = (a0.y + a1.y) + (a2.y + a3.y);
    tt.z = (a0.z + a1.z) + (a2.z + a3.z);
    tt.w = (a0.w + a1.w) + (a2.w + a3.w);
    tt.x += __shfl_xor(tt.x, 32);
    tt.y += __shfl_xor(tt.y, 32);
    tt.z += __shfl_xor(tt.z, 32);
    tt.w += __shfl_xor(tt.w, 32);

    if (h == 0) {
        float dvv = dinv[d];
        us4 r;
        r[0] = f2bf(fmaxf(0.f, tt.x * dvv + bb.x));
        r[1] = f2bf(fmaxf(0.f, tt.y * dvv + bb.y));
        r[2] = f2bf(fmaxf(0.f, tt.z * dvv + bb.z));
        r[3] = f2bf(fmaxf(0.f, tt.w * dvv + bb.w));
        *(us4*)(outX + (size_t)d * KD + sl * 4) = r;
    }
}

// ---------------- cooperative mono-kernel: all 8 phases, 7 grid syncs ------------
__global__ __launch_bounds__(256, 4) void mono_k(
    const float* x, const int* esrc, const int* edst,
    const float* W1, const float* b1, const float* W2, const float* b2,
    const float* Wp, const float* bp, float* out,
    unsigned short* A, unsigned short* X2, float* dinv,
    int* beg, int* endp, int* col, unsigned int* pairs, int* bcur,
    unsigned short* Wh, unsigned short* Wl)
{
    cg::grid_group grid = cg::this_grid();
    __shared__ int smem[1024];
    const int t   = threadIdx.x;
    const int bid = blockIdx.x;
    const int ng  = gridDim.x;
    const int wave = t >> 6, lane = t & 63;
    const int h = lane >> 5, sl = lane & 31;

    // ---- P0: zero cursors (block 0) + W pre-split (blocks 1..160)
    if (bid == 0) {
        if (t < NBUK) bcur[t] = 0;
    } else if (bid <= 160) {
        int i = (bid - 1) * 256 + t;
        if (i < 40960) {
            float w = (i < 16384) ? W1[i] : ((i < 32768) ? W2[i - 16384] : Wp[i - 32768]);
            short hh, ll; splitbf(w, hh, ll);
            Wh[i] = (unsigned short)hh; Wl[i] = (unsigned short)ll;
        }
    }
    grid.sync();

    // ---- P1: bscat (391 chunks)
    {
        int* hh = smem; int* base = smem + NBUK; int* cur = smem + 2 * NBUK;
        for (int vb = bid; vb < NCH; vb += ng) {
            for (int i = t; i < NBUK; i += 256) { hh[i] = 0; cur[i] = 0; }
            __syncthreads();
            int e0 = vb * CHUNK, e1 = min(e0 + CHUNK, NE);
            for (int i = e0 + t; i < e1; i += 256) atomicAdd(&hh[edst[i] >> 8], 1);
            __syncthreads();
            for (int i = t; i < NBUK; i += 256) base[i] = hh[i] ? atomicAdd(&bcur[i], hh[i]) : 0;
            __syncthreads();
            for (int i = e0 + t; i < e1; i += 256) {
                int d = edst[i];
                int b = d >> 8;
                int r = atomicAdd(&cur[b], 1);
                pairs[(size_t)b * SLACK + base[b] + r] = (unsigned)esrc[i] | ((unsigned)(d & 255) << 16);
            }
            __syncthreads();
        }
    }
    grid.sync();

    // ---- P2: bbuild (196 buckets)
    {
        int* hh = smem; int* cur = smem + 256; int* exc = smem + 512; int* sh = smem + 768;
        for (int b = bid; b < NBUK; b += ng) {
            int nb = bcur[b];
            size_t rb = (size_t)b * SLACK;
            int d0 = b << 8;
            int nd = NN - d0; if (nd > 256) nd = 256;
            hh[t] = 0; cur[t] = 0;
            __syncthreads();
            for (int i = t; i < nb; i += 256) atomicAdd(&hh[(pairs[rb + i] >> 16) & 255], 1);
            __syncthreads();
            int v = hh[t];
            sh[t] = v; __syncthreads();
            for (int off = 1; off < 256; off <<= 1) {
                int u = (t >= off) ? sh[t - off] : 0;
                __syncthreads();
                sh[t] += u;
                __syncthreads();
            }
            int ex = sh[t] - v;
            exc[t] = ex;
            if (t < nd) {
                beg[d0 + t]  = (int)rb + ex;
                endp[d0 + t] = (int)rb + ex + v;
                dinv[d0 + t] = rsqrtf(1.0f + (float)v);
            }
            __syncthreads();
            for (int i = t; i < nb; i += 256) {
                unsigned p = pairs[rb + i];
                int dl = (p >> 16) & 255;
                int r = atomicAdd(&cur[dl], 1);
                col[rb + exc[dl] + r] = (int)(p & 0xFFFFu);
            }
            __syncthreads();
        }
    }
    grid.sync();

    const int NV = (NN + 63) / 64;     // 782
    const int nwaves = ng * 4;
    const int gwave  = bid * 4 + wave;
    const unsigned short* hpA  = A  + sl * 4;
    const unsigned short* hpA2 = X2 + sl * 4;   // note: gather2 reads A (see below)

    // ---- P3: layer-1 GEMM: A = bf16((x @ W1^T)*dinv)
    for (int vb = bid; vb < NV; vb += ng)
        mgemm_body<128, false, 0>(x, Wh, Wl, dinv, nullptr, A, vb, t);
    grid.sync();

    // ---- P4: gather1: X2 = relu(dinv*(A+sum)+b1) bf16
    {
        float4 bb = *(const float4*)(b1 + sl * 4);
        for (int d = gwave; d < NN; d += nwaves)
            gather_node(hpA, X2, beg, endp, col, dinv, bb, d, h, sl);
    }
    grid.sync();

    // ---- P5: layer-2 GEMM: A = bf16((X2 @ W2^T)*dinv)
    for (int vb = bid; vb < NV; vb += ng)
        mgemm_body<128, true, 0>(X2, Wh + 16384, Wl + 16384, dinv, nullptr, A, vb, t);
    grid.sync();

    // ---- P6: gather2: X2 = relu(dinv*(A+sum)+b2) bf16
    {
        float4 bb = *(const float4*)(b2 + sl * 4);
        for (int d = gwave; d < NN; d += nwaves)
            gather_node(hpA, X2, beg, endp, col, dinv, bb, d, h, sl);
    }
    grid.sync();

    // ---- P7: head: out = relu(X2 @ Wp^T + bp) fp32
    for (int vb = bid; vb < NV; vb += ng)
        mgemm_body<64, true, 1>(X2, Wh + 32768, Wl + 32768, dinv, bp, out, vb, t);
    (void)hpA2;
}

// ---------------- fallback standalone kernels (R16-proven path) ----------------
__global__ __launch_bounds__(256) void wsplit_k(
    const float* __restrict__ W1, const float* __restrict__ W2, const float* __restrict__ Wp,
    unsigned short* __restrict__ Wh, unsigned short* __restrict__ Wl, int* __restrict__ bcur)
{
    int t = threadIdx.x;
    if (blockIdx.x == 0 && t < NBUK) bcur[t] = 0;
    int i = blockIdx.x * 256 + t;
    if (i < 40960) {
        float w = (i < 16384) ? W1[i] : ((i < 32768) ? W2[i - 16384] : Wp[i - 32768]);
        short h, l; splitbf(w, h, l);
        Wh[i] = (unsigned short)h; Wl[i] = (unsigned short)l;
    }
}
__global__ __launch_bounds__(256) void bscat_k(const int* __restrict__ src, const int* __restrict__ dst,
    int* __restrict__ bcur, unsigned int* __restrict__ pairs, int e)
{
    __shared__ int h[NBUK], base[NBUK], cur[NBUK];
    int t = threadIdx.x;
    int e0 = blockIdx.x * CHUNK, e1 = min(e0 + CHUNK, e);
    for (int i = t; i < NBUK; i += 256) { h[i] = 0; cur[i] = 0; }
    __syncthreads();
    for (int i = e0 + t; i < e1; i += 256) atomicAdd(&h[dst[i] >> 8], 1);
    __syncthreads();
    for (int i = t; i < NBUK; i += 256) base[i] = h[i] ? atomicAdd(&bcur[i], h[i]) : 0;
    __syncthreads();
    for (int i = e0 + t; i < e1; i += 256) {
        int d = dst[i];
        int b = d >> 8;
        int r = atomicAdd(&cur[b], 1);
        pairs[(size_t)b * SLACK + base[b] + r] = (unsigned)src[i] | ((unsigned)(d & 255) << 16);
    }
}
__global__ __launch_bounds__(256) void bbuild_k(const unsigned int* __restrict__ pairs,
    const int* __restrict__ bcur, int* __restrict__ beg, int* __restrict__ endp,
    float* __restrict__ dinv, int* __restrict__ col)
{
    __shared__ int h[256], cur[256], exc[256], sh[256];
    int b = blockIdx.x, t = threadIdx.x;
    int nb = bcur[b];
    size_t rb = (size_t)b * SLACK;
    int d0 = b << 8;
    int nd = NN - d0; if (nd > 256) nd = 256;
    h[t] = 0; cur[t] = 0;
    __syncthreads();
    for (int i = t; i < nb; i += 256) atomicAdd(&h[(pairs[rb + i] >> 16) & 255], 1);
    __syncthreads();
    int v = h[t];
    sh[t] = v; __syncthreads();
    for (int off = 1; off < 256; off <<= 1) {
        int u = (t >= off) ? sh[t - off] : 0;
        __syncthreads();
        sh[t] += u;
        __syncthreads();
    }
    int ex = sh[t] - v;
    exc[t] = ex;
    if (t < nd) {
        beg[d0 + t]  = (int)rb + ex;
        endp[d0 + t] = (int)rb + ex + v;
        dinv[d0 + t] = rsqrtf(1.0f + (float)v);
    }
    __syncthreads();
    for (int i = t; i < nb; i += 256) {
        unsigned p = pairs[rb + i];
        int dl = (p >> 16) & 255;
        int r = atomicAdd(&cur[dl], 1);
        col[rb + exc[dl] + r] = (int)(p & 0xFFFFu);
    }
}
template<int CO, bool XBF, int EPI>
__global__ __launch_bounds__(256) void mgemm_k(
    const void* __restrict__ Xin,
    const unsigned short* __restrict__ Wh, const unsigned short* __restrict__ Wl,
    const float* __restrict__ dinv, const float* __restrict__ bout, void* __restrict__ outAv)
{
    mgemm_body<CO, XBF, EPI>(Xin, Wh, Wl, dinv, bout, outAv, blockIdx.x, threadIdx.x);
}
__global__ __launch_bounds__(256) void gather_k(
    const unsigned short* __restrict__ Hs, unsigned short* __restrict__ outX,
    const int* __restrict__ begp, const int* __restrict__ endpp, const int* __restrict__ col,
    const float* __restrict__ dinv, const float* __restrict__ bias)
{
    int wave = threadIdx.x >> 6;
    int lane = threadIdx.x & 63;
    int h = lane >> 5, sl = lane & 31;
    int d = blockIdx.x * 4 + wave;
    if (d >= NN) return;
    float4 bb = *(const float4*)(bias + sl * 4);
    gather_node(Hs + sl * 4, outX, begp, endpp, col, dinv, bb, d, h, sl);
}

extern "C" void kernel_launch(void* const* d_in, const int* in_sizes, int n_in,
                              void* d_out, int out_size, void* d_ws, size_t ws_size,
                              hipStream_t stream) {
    const float* x    = (const float*)d_in[0];
    const int*   ei   = (const int*)d_in[1];
    const float* W1   = (const float*)d_in[2];
    const float* b1   = (const float*)d_in[3];
    const float* W2   = (const float*)d_in[4];
    const float* b2   = (const float*)d_in[5];
    const float* Wp   = (const float*)d_in[6];
    const float* bp   = (const float*)d_in[7];
    float* out = (float*)d_out;

    const int* esrc = ei;
    const int* edst = ei + NE;

    unsigned short* A  = (unsigned short*)d_ws;
    unsigned short* X2 = A + (size_t)NN * KD;
    float* dinv   = (float*)(X2 + (size_t)NN * KD);
    int*   beg    = (int*)(dinv + NN);
    int*   endp   = beg + NN;
    int*   col    = endp + NN;
    unsigned int* pairs = (unsigned int*)(col + NBUK * SLACK);
    int*   bcur   = (int*)(pairs + (size_t)NBUK * SLACK);
    unsigned short* Wh = (unsigned short*)(bcur + NBUK);
    unsigned short* Wl = Wh + 40960;

    // ---- try cooperative mono-kernel ----
    void* args[] = {
        (void*)&x, (void*)&esrc, (void*)&edst,
        (void*)&W1, (void*)&b1, (void*)&W2, (void*)&b2,
        (void*)&Wp, (void*)&bp, (void*)&out,
        (void*)&A, (void*)&X2, (void*)&dinv,
        (void*)&beg, (void*)&endp, (void*)&col, (void*)&pairs, (void*)&bcur,
        (void*)&Wh, (void*)&Wl
    };
    hipError_t err = hipLaunchCooperativeKernel((void*)mono_k, dim3(GBLK), dim3(256),
                                                args, 0, stream);
    if (err == hipSuccess) return;

    // ---- fallback: R16-proven 8-dispatch path ----
    const int GB = (NN + 63) / 64;
    const int AB = (NN + 3) / 4;
    wsplit_k<<<160, 256, 0, stream>>>(W1, W2, Wp, Wh, Wl, bcur);
    bscat_k <<<NCH, 256, 0, stream>>>(esrc, edst, bcur, pairs, NE);
    bbuild_k<<<NBUK, 256, 0, stream>>>(pairs, bcur, beg, endp, dinv, col);
    mgemm_k<128, false, 0><<<GB, 256, 0, stream>>>(x, Wh, Wl, dinv, nullptr, A);
    gather_k<<<AB, 256, 0, stream>>>(A, X2, beg, endp, col, dinv, b1);
    mgemm_k<128, true, 0><<<GB, 256, 0, stream>>>(X2, Wh + 16384, Wl + 16384, dinv, nullptr, A);
    gather_k<<<AB, 256, 0, stream>>>(A, X2, beg, endp, col, dinv, b2);
    mgemm_k<64, true, 1><<<GB, 256, 0, stream>>>(X2, Wh + 32768, Wl + 32768, dinv, bp, out);
}

// Round 18
// 163.998 us; speedup vs baseline: 7.2386x; 7.2386x over previous
//
#include <hip/hip_runtime.h>

#define NN 50000
#define NE 800000
#define KD 128    // inner dim (IN_C == HID_C == 128)
#define NBUK 196  // ceil(NN/256) buckets by dst>>8
#define CHUNK 2048
#define SLACK 8192  // fixed bucket region size (mean 4082, +64 sigma safe)

typedef __attribute__((ext_vector_type(8))) short short8;
typedef __attribute__((ext_vector_type(4))) float f32x4;
typedef __attribute__((ext_vector_type(4))) unsigned short us4;

// ---------------- bf16 helpers ----------------
__device__ inline void splitbf(float x, short& h, short& l) {
    unsigned int u = __float_as_uint(x);
    unsigned int r = u + 0x8000u;                 // round-to-nearest on hi
    short hh = (short)(r >> 16);
    float hf = __uint_as_float(((unsigned int)(unsigned short)hh) << 16);
    float lo = x - hf;
    unsigned int u2 = __float_as_uint(lo) + 0x8000u;
    h = hh;
    l = (short)(u2 >> 16);
}
__device__ inline unsigned short f2bf(float x) {   // RTNE
    unsigned int u = __float_as_uint(x);
    unsigned int r = u + 0x7FFFu + ((u >> 16) & 1u);
    return (unsigned short)(r >> 16);
}
__device__ inline float bf2f(unsigned short b) {
    return __uint_as_float(((unsigned int)b) << 16);
}

// ---------------- W pre-split: all three weights -> bf16 hi/lo (RTNE, once) -------
// layout: [W1: 16384][W2: 16384][Wp: 8192] row-major [c][k]
// block 0 also zeroes the bucket cursors (completes before bscat_k launches).
__global__ __launch_bounds__(256) void wsplit_k(
    const float* __restrict__ W1, const float* __restrict__ W2, const float* __restrict__ Wp,
    unsigned short* __restrict__ Wh, unsigned short* __restrict__ Wl,
    int* __restrict__ bcur)
{
    int t = threadIdx.x;
    if (blockIdx.x == 0 && t < NBUK) bcur[t] = 0;
    int i = blockIdx.x * 256 + t;                  // 0..40959
    float w;
    if (i < 16384) w = W1[i];
    else if (i < 32768) w = W2[i - 16384];
    else w = Wp[i - 32768];
    short h, l;
    splitbf(w, h, l);
    Wh[i] = (unsigned short)h;
    Wl[i] = (unsigned short)l;
}

// ---------------- CSR build: direct-bucket counting sort ----------------
__global__ __launch_bounds__(256) void bscat_k(const int* __restrict__ src, const int* __restrict__ dst,
    int* __restrict__ bcur, unsigned int* __restrict__ pairs, int e)
{
    __shared__ int h[NBUK], base[NBUK], cur[NBUK];
    int t = threadIdx.x;
    int e0 = blockIdx.x * CHUNK, e1 = min(e0 + CHUNK, e);
    for (int i = t; i < NBUK; i += 256) { h[i] = 0; cur[i] = 0; }
    __syncthreads();
    for (int i = e0 + t; i < e1; i += 256) atomicAdd(&h[dst[i] >> 8], 1);
    __syncthreads();
    for (int i = t; i < NBUK; i += 256) base[i] = h[i] ? atomicAdd(&bcur[i], h[i]) : 0;
    __syncthreads();
    for (int i = e0 + t; i < e1; i += 256) {
        int d = dst[i];
        int b = d >> 8;
        int r = atomicAdd(&cur[b], 1);
        pairs[(size_t)b * SLACK + base[b] + r] = (unsigned)src[i] | ((unsigned)(d & 255) << 16);
    }
}
__global__ __launch_bounds__(256) void bbuild_k(const unsigned int* __restrict__ pairs,
    const int* __restrict__ bcur,
    int* __restrict__ beg, int* __restrict__ endp, float* __restrict__ dinv,
    int* __restrict__ col)
{
    __shared__ int h[256], cur[256], exc[256], sh[256];
    int b = blockIdx.x, t = threadIdx.x;
    int nb = bcur[b];
    size_t rb = (size_t)b * SLACK;
    int d0 = b << 8;
    int nd = NN - d0; if (nd > 256) nd = 256;
    h[t] = 0; cur[t] = 0;
    __syncthreads();
    for (int i = t; i < nb; i += 256) atomicAdd(&h[(pairs[rb + i] >> 16) & 255], 1);
    __syncthreads();
    int v = h[t];
    sh[t] = v; __syncthreads();
    for (int off = 1; off < 256; off <<= 1) {
        int u = (t >= off) ? sh[t - off] : 0;
        __syncthreads();
        sh[t] += u;
        __syncthreads();
    }
    int ex = sh[t] - v;
    exc[t] = ex;
    if (t < nd) {
        beg[d0 + t]  = (int)rb + ex;
        endp[d0 + t] = (int)rb + ex + v;
        dinv[d0 + t] = rsqrtf(1.0f + (float)v);
    }
    __syncthreads();
    for (int i = t; i < nb; i += 256) {
        unsigned p = pairs[rb + i];
        int dl = (p >> 16) & 255;
        int r = atomicAdd(&cur[dl], 1);
        col[rb + exc[dl] + r] = (int)(p & 0xFFFFu);
    }
}

// ---------------- MFMA GEMM: outA[n,c] = epi( sum_k Xin[n,k] * W[c,k] ) --------
// W pre-split bf16 hi/lo in global; staged (pure copy) into XOR-swizzled LDS.
// XBF=false: X fp32, 3-term (xh*wh + xh*wl + xl*wh)  [layer 1]
// XBF=true:  X already bf16, 2-term (x*wh + x*wl)    [layer 2, head]
// EPI==0: write (acc*dinv[row]) bf16 (gather source); EPI==1: relu(acc+bout) fp32
template<int CO, bool XBF, int EPI>
__global__ __launch_bounds__(256) void mgemm_k(
    const void* __restrict__ Xin,
    const unsigned short* __restrict__ Wh, const unsigned short* __restrict__ Wl,
    const float* __restrict__ dinv,
    const float* __restrict__ bout, void* __restrict__ outAv)
{
    __shared__ short8 WhV[CO * 16];   // [c][granule], granule = 8 bf16 of k
    __shared__ short8 WlV[CO * 16];   // XOR-swizzled: slot = G ^ (c & 15)

    const int t = threadIdx.x;

    for (int i = t; i < CO * 16; i += 256) {
        int c = i >> 4, G = i & 15;
        short8 h = *(const short8*)(Wh + c * KD + G * 8);
        short8 l = *(const short8*)(Wl + c * KD + G * 8);
        int Gs = G ^ (c & 15);
        WhV[c * 16 + Gs] = h;
        WlV[c * 16 + Gs] = l;
    }
    __syncthreads();

    const int wv = t >> 6, l = t & 63, q = l >> 4, lr = l & 15;
    const int row0 = blockIdx.x * 64 + wv * 16;
    constexpr int NCT = CO / 16;

    f32x4 acc[NCT];
#pragma unroll
    for (int ct = 0; ct < NCT; ++ct) acc[ct] = (f32x4){0.f, 0.f, 0.f, 0.f};

    int xrow = row0 + lr; if (xrow > NN - 1) xrow = NN - 1;   // clamp (stores guarded)

#pragma unroll
    for (int kk = 0; kk < 4; ++kk) {
        short8 ah, al;
        if (XBF) {
            ah = *(const short8*)((const unsigned short*)Xin + (size_t)xrow * KD + q * 8 + kk * 32);
        } else {
            const float* xbase = (const float*)Xin + (size_t)xrow * KD + q * 8 + kk * 32;
            float4 x0 = *(const float4*)xbase;
            float4 x1 = *(const float4*)(xbase + 4);
            float xs[8] = {x0.x, x0.y, x0.z, x0.w, x1.x, x1.y, x1.z, x1.w};
#pragma unroll
            for (int j = 0; j < 8; ++j) { short hh, ll; splitbf(xs[j], hh, ll); ah[j] = hh; al[j] = ll; }
        }

#pragma unroll
        for (int ct = 0; ct < NCT; ++ct) {
            int c = ct * 16 + lr;
            int Gs = (kk * 4 + q) ^ (c & 15);
            short8 bh = WhV[c * 16 + Gs];
            short8 bl = WlV[c * 16 + Gs];
            acc[ct] = __builtin_amdgcn_mfma_f32_16x16x32_bf16(ah, bh, acc[ct], 0, 0, 0);
            acc[ct] = __builtin_amdgcn_mfma_f32_16x16x32_bf16(ah, bl, acc[ct], 0, 0, 0);
            if (!XBF)
                acc[ct] = __builtin_amdgcn_mfma_f32_16x16x32_bf16(al, bh, acc[ct], 0, 0, 0);
        }
    }

    // ---- epilogue: D[row=(q*4+r)][col=lane&15] per C/D mapping
    float dv[4]; int rok[4];
#pragma unroll
    for (int r = 0; r < 4; ++r) {
        int row = row0 + q * 4 + r;
        rok[r] = (row < NN);
        dv[r] = (EPI == 0 && rok[r]) ? dinv[row] : 0.f;
    }
#pragma unroll
    for (int ct = 0; ct < NCT; ++ct) {
        int c = ct * 16 + lr;
        float bc = (EPI == 1) ? bout[c] : 0.f;
#pragma unroll
        for (int r = 0; r < 4; ++r) {
            int row = row0 + q * 4 + r;
            if (rok[r]) {
                float v = acc[ct][r];
                if (EPI == 0) {
                    ((unsigned short*)outAv)[(size_t)row * CO + c] = f2bf(v * dv[r]);
                } else {
                    ((float*)outAv)[(size_t)row * CO + c] = fmaxf(0.f, v + bc);
                }
            }
        }
    }
}

// ---------------- CSR gather + next-layer input transform -----------------
// outX[d,:] = relu( dinv[d]*(A[d,:] + sum_{s in adj(d)} A[s,:]) + bias ) as bf16
// A bf16 [N][128]. Direct col[j] loads, parity halves, 4-deep unroll (R9-proven).
__global__ __launch_bounds__(256) void gather_k(
    const unsigned short* __restrict__ Hs, unsigned short* __restrict__ outX,
    const int* __restrict__ begp, const int* __restrict__ endpp,
    const int* __restrict__ col,
    const float* __restrict__ dinv, const float* __restrict__ bias)
{
    int wave = threadIdx.x >> 6;
    int lane = threadIdx.x & 63;
    int h  = lane >> 5;          // neighbor parity handled by this half-wave
    int sl = lane & 31;          // channel chunk: channels [4*sl, 4*sl+3]
    int d = blockIdx.x * 4 + wave;
    if (d >= NN) return;
    int beg = begp[d], end = endpp[d];

    const unsigned short* hp = Hs + sl * 4;
    float4 bb = *(const float4*)(bias + sl * 4);

    float4 a0 = make_float4(0.f, 0.f, 0.f, 0.f);
    float4 a1 = make_float4(0.f, 0.f, 0.f, 0.f);
    float4 a2 = make_float4(0.f, 0.f, 0.f, 0.f);
    float4 a3 = make_float4(0.f, 0.f, 0.f, 0.f);

    if (h == 0) {                                   // self-loop term on even half
        us4 v = *(const us4*)(hp + (size_t)d * KD);
        a0.x = bf2f(v[0]); a0.y = bf2f(v[1]); a0.z = bf2f(v[2]); a0.w = bf2f(v[3]);
    }

    int j = beg + h;
    for (; j + 6 < end; j += 8) {                   // 4-deep, stride 2 per half
        int s0 = col[j],     s1 = col[j + 2];
        int s2 = col[j + 4], s3 = col[j + 6];
        us4 v0 = *(const us4*)(hp + (size_t)s0 * KD);
        us4 v1 = *(const us4*)(hp + (size_t)s1 * KD);
        us4 v2 = *(const us4*)(hp + (size_t)s2 * KD);
        us4 v3 = *(const us4*)(hp + (size_t)s3 * KD);
        a0.x += bf2f(v0[0]); a0.y += bf2f(v0[1]); a0.z += bf2f(v0[2]); a0.w += bf2f(v0[3]);
        a1.x += bf2f(v1[0]); a1.y += bf2f(v1[1]); a1.z += bf2f(v1[2]); a1.w += bf2f(v1[3]);
        a2.x += bf2f(v2[0]); a2.y += bf2f(v2[1]); a2.z += bf2f(v2[2]); a2.w += bf2f(v2[3]);
        a3.x += bf2f(v3[0]); a3.y += bf2f(v3[1]); a3.z += bf2f(v3[2]); a3.w += bf2f(v3[3]);
    }
    for (; j < end; j += 2) {                       // remainder (same parity)
        int s = col[j];
        us4 v = *(const us4*)(hp + (size_t)s * KD);
        a0.x += bf2f(v[0]); a0.y += bf2f(v[1]); a0.z += bf2f(v[2]); a0.w += bf2f(v[3]);
    }

    float4 tt;
    tt.x = (a0.x + a1.x) + (a2.x + a3.x);
    tt.y = (a0.y + a1.y) + (a2.y + a3.y);
    tt.z = (a0.z + a1.z) + (a2.z + a3.z);
    tt.w = (a0.w + a1.w) + (a2.w + a3.w);
    tt.x += __shfl_xor(tt.x, 32);                   // combine parities across halves
    tt.y += __shfl_xor(tt.y, 32);
    tt.z += __shfl_xor(tt.z, 32);
    tt.w += __shfl_xor(tt.w, 32);

    if (h == 0) {
        float dvv = dinv[d];
        us4 r;
        r[0] = f2bf(fmaxf(0.f, tt.x * dvv + bb.x));
        r[1] = f2bf(fmaxf(0.f, tt.y * dvv + bb.y));
        r[2] = f2bf(fmaxf(0.f, tt.z * dvv + bb.z));
        r[3] = f2bf(fmaxf(0.f, tt.w * dvv + bb.w));
        *(us4*)(outX + (size_t)d * KD + sl * 4) = r;
    }
}

extern "C" void kernel_launch(void* const* d_in, const int* in_sizes, int n_in,
                              void* d_out, int out_size, void* d_ws, size_t ws_size,
                              hipStream_t stream) {
    const float* x    = (const float*)d_in[0];
    const int*   ei   = (const int*)d_in[1];     // [2,E] int32
    const float* W1   = (const float*)d_in[2];
    const float* b1   = (const float*)d_in[3];
    const float* W2   = (const float*)d_in[4];
    const float* b2   = (const float*)d_in[5];
    const float* Wp   = (const float*)d_in[6];
    const float* bp   = (const float*)d_in[7];
    float* out = (float*)d_out;

    const int* esrc = ei;
    const int* edst = ei + NE;

    unsigned short* A  = (unsigned short*)d_ws;       // bf16 Hs       [N,128] 12.8 MB
    unsigned short* X2 = A + (size_t)NN * KD;         // bf16 next-X   [N,128] 12.8 MB
    float* dinv   = (float*)(X2 + (size_t)NN * KD);   // [N]
    int*   beg    = (int*)(dinv + NN);                // [N]
    int*   endp   = beg + NN;                         // [N]
    int*   col    = endp + NN;                        // [NBUK*SLACK] 6.4 MB
    unsigned int* pairs = (unsigned int*)(col + NBUK * SLACK); // [NBUK*SLACK] 6.4 MB
    int*   bcur   = (int*)(pairs + (size_t)NBUK * SLACK);      // [NBUK]
    unsigned short* Wh = (unsigned short*)(bcur + NBUK);       // [40960]
    unsigned short* Wl = Wh + 40960;                           // [40960]

    const int NCH = (NE + CHUNK - 1) / CHUNK;         // 391

    // ---- W pre-split (+ cursor zero in block 0) ----
    wsplit_k<<<160, 256, 0, stream>>>(W1, W2, Wp, Wh, Wl, bcur);
    // ---- CSR by dst (+ dinv) via direct-bucket counting sort ----
    bscat_k <<<NCH, 256, 0, stream>>>(esrc, edst, bcur, pairs, NE);
    bbuild_k<<<NBUK, 256, 0, stream>>>(pairs, bcur, beg, endp, dinv, col);

    const int GB = (NN + 63) / 64;      // 782 mfma-gemm blocks
    const int AB = (NN + 3) / 4;        // 12500 gather blocks (4 waves/block)

    // layer 1: Hs1 = (x@W1^T)*dinv -> A (bf16)
    mgemm_k<128, false, 0><<<GB, 256, 0, stream>>>(x, Wh, Wl, dinv, nullptr, A);
    // gather + transform: X2 = relu(dinv*(A+sum) + b1)  (bf16)
    gather_k<<<AB, 256, 0, stream>>>(A, X2, beg, endp, col, dinv, b1);
    // layer 2: Hs2 = (X2@W2^T)*dinv -> A (bf16), 2-term MFMA
    mgemm_k<128, true, 0><<<GB, 256, 0, stream>>>(X2, Wh + 16384, Wl + 16384, dinv, nullptr, A);
    // gather + transform: X2 = relu(dinv*(A+sum) + b2)  (bf16)
    gather_k<<<AB, 256, 0, stream>>>(A, X2, beg, endp, col, dinv, b2);
    // head: out = relu(X2@Wp^T + bp)  fp32
    mgemm_k<64, true, 1><<<GB, 256, 0, stream>>>(X2, Wh + 32768, Wl + 32768, dinv, bp, out);
}